// Round 6
// baseline (897.583 us; speedup 1.0000x reference)
//
#include <hip/hip_runtime.h>

#define SEQ_L 4096
#define HDIM  30
#define DEC_N 100
#define HSTR  33   // padded history stride (bank-conflict-free final reads)

typedef float v2f __attribute__((ext_vector_type(2)));
typedef unsigned int v2u __attribute__((ext_vector_type(2)));

#define NLc (-1.44269504088896340736f)   // -log2(e): sigmoid prescale
#define TLc ( 2.88539008177792681472f)   // 2*log2(e): tanh prescale

__device__ __forceinline__ float sig2(float sp) {   // sp = NLc * x  -> sigmoid(x)
    return __builtin_amdgcn_rcpf(1.0f + __builtin_amdgcn_exp2f(sp));
}
__device__ __forceinline__ float tanh2(float tp) {  // tp = TLc * x  -> tanh(x)
    return fmaf(-2.0f, __builtin_amdgcn_rcpf(1.0f + __builtin_amdgcn_exp2f(tp)), 1.0f);
}
__device__ __forceinline__ v2f mk2(float a, float b) { v2f r; r.x = a; r.y = b; return r; }

// lane-l result = p[l] + p[l^32], via VALU permlane (no DS pipe).
__device__ __forceinline__ float combine32(float p) {
    v2u r = __builtin_amdgcn_permlane32_swap(__float_as_uint(p), __float_as_uint(p),
                                             false, false);
    return __uint_as_float(r.x) + __uint_as_float(r.y);
}
// Pull h from lane (idx/4) register file — no LDS store needed.
__device__ __forceinline__ float bperm(int idx, float v) {
    return __int_as_float(__builtin_amdgcn_ds_bpermute(idx, __float_as_int(v)));
}

// One block, one wave. Unit j handled by lanes j (k=0..15) and j+32 (k=16..29).
// h lives ONLY in registers: after combine32 every lane k holds h_k; each step
// the 16 needed values are pulled via ds_bpermute (register crossbar, single
// DS latency, no write->read round trip).
__global__ __launch_bounds__(64, 1) void seq2seq_gru_kernel(
    const float* __restrict__ x,
    const float* __restrict__ eWih, const float* __restrict__ eWhh,
    const float* __restrict__ ebih, const float* __restrict__ ebhh,
    const float* __restrict__ dWih, const float* __restrict__ dWhh,
    const float* __restrict__ dbih, const float* __restrict__ dbhh,
    const float* __restrict__ linW, const float* __restrict__ linb,
    float* __restrict__ out)
{
    const int t    = threadIdx.x;
    const int l    = t & 31;
    const int half = t >> 5;
    const int j    = (l < HDIM) ? l : (HDIM - 1);
    const int wslot = (l < HDIM) ? l : (HDIM - 1);

    __shared__ __align__(16) float xs[SEQ_L + 4];
    __shared__ __align__(16) float hist[DEC_N * HSTR];
    __shared__ __align__(16) float lws[32];

    {   // stage x (vectorized); zero prefetch pad; stage linW
        const float4* x4 = (const float4*)x;
        float4* s4 = (float4*)xs;
        #pragma unroll 4
        for (int i = t; i < SEQ_L / 4; i += 64) s4[i] = x4[i];
        if (t < 4) xs[SEQ_L + t] = 0.0f;
        if (t < 32) lws[t] = (t < HDIM) ? linW[t] : 0.0f;
    }

    // bpermute byte-indices for this lane's k-range (clamped slots have 0 weights)
    int bidx[16];
    #pragma unroll
    for (int m = 0; m < 16; ++m) {
        const int kk = half * 16 + m;
        bidx[m] = ((kk < HDIM) ? kk : (HDIM - 1)) * 4;
    }

    // ---- encoder weights: prescaled v2f pairs, zero-padded past k=29 ----
    v2f wr2[8], wz2[8], wn2[8];
    {
        const float* Rr = eWhh + (j         ) * HDIM;
        const float* Rz = eWhh + (j +  HDIM ) * HDIM;
        const float* Rn = eWhh + (j + 2*HDIM) * HDIM;
        #pragma unroll
        for (int m = 0; m < 8; ++m) {
            const int k = half * 16 + 2 * m;
            float r0=0.f,r1=0.f,z0=0.f,z1=0.f,n0=0.f,n1=0.f;
            if (k     < HDIM) { r0 = Rr[k];   z0 = Rz[k];   n0 = Rn[k];   }
            if (k + 1 < HDIM) { r1 = Rr[k+1]; z1 = Rz[k+1]; n1 = Rn[k+1]; }
            wr2[m] = mk2(NLc * r0, NLc * r1);
            wz2[m] = mk2(NLc * z0, NLc * z1);
            wn2[m] = mk2(TLc * n0, TLc * n1);
        }
    }
    // per-half init constants: x-terms and biases live on half 1 only
    const float wirN = half ? NLc * eWih[j]        : 0.f;
    const float wizN = half ? NLc * eWih[j + HDIM] : 0.f;
    const float brN  = half ? NLc * (ebih[j] + ebhh[j]) : 0.f;
    const float bzN  = half ? NLc * (ebih[j + HDIM] + ebhh[j + HDIM]) : 0.f;
    const float bnN  = half ? TLc * ebhh[j + 2*HDIM] : 0.f;
    const float win_ = TLc * eWih[j + 2*HDIM];
    const float bni  = TLc * ebih[j + 2*HDIM];

    __syncthreads();    // xs/lws staged (one-time)

    float hj = 0.0f;    // lane's unit value (lanes l and l+32 agree)
    float xr = xs[0];

    // ================= encoder: 4096 sequential GRU steps =================
    #pragma unroll 2
    for (int s = 0; s < SEQ_L; ++s) {
        const float xnext = xs[s + 1];
        v2f g2[8];
        #pragma unroll
        for (int m = 0; m < 8; ++m) {
            g2[m].x = bperm(bidx[2*m],     hj);
            g2[m].y = bperm(bidx[2*m + 1], hj);
        }
        v2f aA = mk2(fmaf(xr, wirN, brN), 0.f);
        v2f bA = mk2(fmaf(xr, wizN, bzN), 0.f);
        v2f cA = mk2(bnN, 0.f);
        aA += g2[0]*wr2[0]; bA += g2[0]*wz2[0]; cA += g2[0]*wn2[0];
        aA += g2[2]*wr2[2]; bA += g2[2]*wz2[2]; cA += g2[2]*wn2[2];
        aA += g2[4]*wr2[4]; bA += g2[4]*wz2[4]; cA += g2[4]*wn2[4];
        aA += g2[6]*wr2[6]; bA += g2[6]*wz2[6]; cA += g2[6]*wn2[6];
        v2f aB = g2[1]*wr2[1], bB = g2[1]*wz2[1], cB = g2[1]*wn2[1];
        aB += g2[3]*wr2[3]; bB += g2[3]*wz2[3]; cB += g2[3]*wn2[3];
        aB += g2[5]*wr2[5]; bB += g2[5]*wz2[5]; cB += g2[5]*wn2[5];
        aB += g2[7]*wr2[7]; bB += g2[7]*wz2[7]; cB += g2[7]*wn2[7];
        const v2f as = aA + aB, bs = bA + bB, cs = cA + cB;
        const float pr = combine32(as.x + as.y);
        const float pz = combine32(bs.x + bs.y);
        const float pn = combine32(cs.x + cs.y);
        const float rg = sig2(pr);
        const float zg = sig2(pz);
        const float ng = tanh2(fmaf(rg, pn, fmaf(xr, win_, bni)));
        hj = fmaf(zg, hj - ng, ng);          // (1-z)*n + z*h
        xr = xnext;
    }
    // hj = h_enc component (all four owner lanes agree)

    // ---- decoder weights: prescaled v2f pairs, zero-padded ----
    v2f ur[8], uz[8], un[8], vr[8], vz[8], vn[8];
    {
        const float* R0 = dWih + (j         ) * HDIM;
        const float* R1 = dWih + (j +  HDIM ) * HDIM;
        const float* R2 = dWih + (j + 2*HDIM) * HDIM;
        const float* R3 = dWhh + (j         ) * HDIM;
        const float* R4 = dWhh + (j +  HDIM ) * HDIM;
        const float* R5 = dWhh + (j + 2*HDIM) * HDIM;
        #pragma unroll
        for (int m = 0; m < 8; ++m) {
            const int k = half * 16 + 2 * m;
            float a0=0,a1=0,b0=0,b1=0,c0=0,c1=0,d0=0,d1=0,e0=0,e1=0,f0=0,f1=0;
            if (k     < HDIM) { a0=R0[k];   b0=R1[k];   c0=R2[k];   d0=R3[k];   e0=R4[k];   f0=R5[k];   }
            if (k + 1 < HDIM) { a1=R0[k+1]; b1=R1[k+1]; c1=R2[k+1]; d1=R3[k+1]; e1=R4[k+1]; f1=R5[k+1]; }
            ur[m] = mk2(NLc*a0, NLc*a1);  uz[m] = mk2(NLc*b0, NLc*b1);  un[m] = mk2(TLc*c0, TLc*c1);
            vr[m] = mk2(NLc*d0, NLc*d1);  vz[m] = mk2(NLc*e0, NLc*e1);  vn[m] = mk2(TLc*f0, TLc*f1);
        }
    }
    // decoder bias init constants (half 1 carries them)
    const float cR  = half ? NLc * (dbih[j] + dbhh[j]) : 0.f;
    const float cZ  = half ? NLc * (dbih[j + HDIM] + dbhh[j + HDIM]) : 0.f;
    const float cIN = half ? TLc * dbih[j + 2*HDIM] : 0.f;
    const float cHN = half ? TLc * dbhh[j + 2*HDIM] : 0.f;
    // Whh row sums (+ all biases) for decoder step 1 (h = ones)
    float vrs = cR, vzs = cZ, vns = cHN;
    #pragma unroll
    for (int m = 0; m < 8; ++m) {
        vrs += vr[m].x + vr[m].y;
        vzs += vz[m].x + vz[m].y;
        vns += vn[m].x + vn[m].y;
    }
    vrs = combine32(vrs);
    vzs = combine32(vzs);
    vns = combine32(vns);
    const float lb = linb[0];

    float hd;
    // ---- decoder step 1: x = h_enc (bpermute of hj), h = ones ----
    {
        v2f g2[8];
        #pragma unroll
        for (int m = 0; m < 8; ++m) {
            g2[m].x = bperm(bidx[2*m],     hj);
            g2[m].y = bperm(bidx[2*m + 1], hj);
        }
        v2f a2 = mk2(cIN, 0.f);   // reuse slot: a2 holds un-chain bias? no:
        // chains: r,z over ur/uz (bias via vrs/vzs after combine), n over un (bias cIN)
        v2f aA = g2[0]*ur[0], bA = g2[0]*uz[0], cA = mk2(cIN,0.f);
        cA += g2[0]*un[0];
        aA += g2[2]*ur[2]; bA += g2[2]*uz[2]; cA += g2[2]*un[2];
        aA += g2[4]*ur[4]; bA += g2[4]*uz[4]; cA += g2[4]*un[4];
        aA += g2[6]*ur[6]; bA += g2[6]*uz[6]; cA += g2[6]*un[6];
        v2f aB = g2[1]*ur[1], bB = g2[1]*uz[1], cB = g2[1]*un[1];
        aB += g2[3]*ur[3]; bB += g2[3]*uz[3]; cB += g2[3]*un[3];
        aB += g2[5]*ur[5]; bB += g2[5]*uz[5]; cB += g2[5]*un[5];
        aB += g2[7]*ur[7]; bB += g2[7]*uz[7]; cB += g2[7]*un[7];
        (void)a2;
        const v2f as = aA + aB, bs = bA + bB, cs = cA + cB;
        const float pr  = combine32(as.x + as.y) + vrs;
        const float pz  = combine32(bs.x + bs.y) + vzs;
        const float pin = combine32(cs.x + cs.y);
        const float rg = sig2(pr), zg = sig2(pz);
        const float ng = tanh2(fmaf(rg, vns, pin));
        hd = fmaf(zg, 1.0f - ng, ng);        // h = 1
        hist[0 * HSTR + wslot] = hd;
    }
    // steps >= 2: x == h -> fuse Wih+Whh for r,z
    #pragma unroll
    for (int m = 0; m < 8; ++m) { ur[m] += vr[m]; uz[m] += vz[m]; }

    // ---- decoder steps 2..100 (outputs deferred) ----
    for (int s = 1; s < DEC_N; ++s) {
        v2f g2[8];
        #pragma unroll
        for (int m = 0; m < 8; ++m) {
            g2[m].x = bperm(bidx[2*m],     hd);
            g2[m].y = bperm(bidx[2*m + 1], hd);
        }
        v2f aA = mk2(cR, 0.f), bA = mk2(cZ, 0.f), cA = mk2(cIN, 0.f), dA = mk2(cHN, 0.f);
        aA += g2[0]*ur[0]; bA += g2[0]*uz[0]; cA += g2[0]*un[0]; dA += g2[0]*vn[0];
        aA += g2[2]*ur[2]; bA += g2[2]*uz[2]; cA += g2[2]*un[2]; dA += g2[2]*vn[2];
        aA += g2[4]*ur[4]; bA += g2[4]*uz[4]; cA += g2[4]*un[4]; dA += g2[4]*vn[4];
        aA += g2[6]*ur[6]; bA += g2[6]*uz[6]; cA += g2[6]*un[6]; dA += g2[6]*vn[6];
        v2f aB = g2[1]*ur[1], bB = g2[1]*uz[1], cB = g2[1]*un[1], dB = g2[1]*vn[1];
        aB += g2[3]*ur[3]; bB += g2[3]*uz[3]; cB += g2[3]*un[3]; dB += g2[3]*vn[3];
        aB += g2[5]*ur[5]; bB += g2[5]*uz[5]; cB += g2[5]*un[5]; dB += g2[5]*vn[5];
        aB += g2[7]*ur[7]; bB += g2[7]*uz[7]; cB += g2[7]*un[7]; dB += g2[7]*vn[7];
        const v2f as = aA + aB, bs = bA + bB, cs = cA + cB, ds = dA + dB;
        const float pr  = combine32(as.x + as.y);
        const float pz  = combine32(bs.x + bs.y);
        const float pin = combine32(cs.x + cs.y);
        const float phn = combine32(ds.x + ds.y);
        const float rg = sig2(pr), zg = sig2(pz);
        const float ng = tanh2(fmaf(rg, phn, pin));
        hd = fmaf(zg, hd - ng, ng);
        hist[s * HSTR + wslot] = hd;
    }

    // ---- outputs: 100 parallel dot products from the LDS history ----
    #pragma unroll
    for (int b = 0; b < 2; ++b) {
        const int s = t + b * 64;
        if (s < DEC_N) {
            const float* hp = hist + s * HSTR;
            float acc = lb;
            #pragma unroll
            for (int k = 0; k < HDIM; ++k) acc = fmaf(lws[k], hp[k], acc);
            out[s] = acc;
        }
    }
}

extern "C" void kernel_launch(void* const* d_in, const int* in_sizes, int n_in,
                              void* d_out, int out_size, void* d_ws, size_t ws_size,
                              hipStream_t stream) {
    (void)in_sizes; (void)n_in; (void)d_ws; (void)ws_size; (void)out_size;
    seq2seq_gru_kernel<<<dim3(1), dim3(64), 0, stream>>>(
        (const float*)d_in[0],
        (const float*)d_in[1], (const float*)d_in[2],
        (const float*)d_in[3], (const float*)d_in[4],
        (const float*)d_in[5], (const float*)d_in[6],
        (const float*)d_in[7], (const float*)d_in[8],
        (const float*)d_in[9], (const float*)d_in[10],
        (float*)d_out);
}